// Round 11
// baseline (102.074 us; speedup 1.0000x reference)
//
#include <hip/hip_runtime.h>
#include <float.h>
#include <math.h>

#define Ln 2048
#define Bn 64
#define Cn 512
#define Qn 512
#define Vn 512
#define NO 1536   // C*KW

#define DROW 2064   // padded dpl row: 8 front pad + 2048 + 8 tail pad
#define DPAD 8

// workspace layout (in floats)
#define OFF_KERN 0                                   // kern[3][B][C]   = 98304
#define OFF_DPL  98304                               // dplP[3][B][DROW]= 396288
#define OFF_ABT  (OFF_DPL + 396288)                  // aBT[b][t]       = 131072
#define OFF_ET   (OFF_ABT + 131072)                  // eT[b][t]        = 131072
#define OFF_CST  (OFF_ET + 131072)                   // cstat[B][16]    = 1024 (64B line per b)
#define OFF_CNT  (OFF_CST + 1024)                    // cnt[B] (int)    = 64
#define OFF_SCR  (OFF_CNT + 64)                      // gpart(393216) / vpart[4][B][V](131072)

typedef float f4 __attribute__((ext_vector_type(4)));
typedef float f2 __attribute__((ext_vector_type(2)));

// ---------------- K1: gpart[ks][b][o] = sum_{k in split} q[b,k] W[o,k]
__global__ __launch_bounds__(256) void k1_gemm(const float* __restrict__ q,
                                               const float* __restrict__ W,
                                               float* __restrict__ gpart) {
    __shared__ __align__(16) float qs[64][68];
    __shared__ __align__(16) float wsm[64][68];
    const int o0 = blockIdx.x * 64;
    const int k0 = blockIdx.y * 128;
    const int tid = threadIdx.x;
    const int ty = tid >> 4, tx = tid & 15;

    f4 accv[4][4];
#pragma unroll
    for (int i = 0; i < 4; ++i)
#pragma unroll
        for (int j = 0; j < 4; ++j) accv[i][j] = (f4)0.f;

    for (int kc = 0; kc < 128; kc += 64) {
#pragma unroll
        for (int r = 0; r < 4; ++r) {
            int idx = tid + r * 256;
            int row = idx >> 4;
            int c4 = (idx & 15) << 2;
            float4 vq = *(const float4*)&q[row * Qn + k0 + kc + c4];
            qs[row][c4 + 0] = vq.x; qs[row][c4 + 1] = vq.y;
            qs[row][c4 + 2] = vq.z; qs[row][c4 + 3] = vq.w;
            float4 vw = *(const float4*)&W[(o0 + row) * Qn + k0 + kc + c4];
            wsm[row][c4 + 0] = vw.x; wsm[row][c4 + 1] = vw.y;
            wsm[row][c4 + 2] = vw.z; wsm[row][c4 + 3] = vw.w;
        }
        __syncthreads();
#pragma unroll
        for (int kk4 = 0; kk4 < 16; ++kk4) {
            f4 qf[4], wf[4];
#pragma unroll
            for (int i = 0; i < 4; ++i) qf[i] = *(const f4*)&qs[ty * 4 + i][kk4 * 4];
#pragma unroll
            for (int j = 0; j < 4; ++j) wf[j] = *(const f4*)&wsm[tx * 4 + j][kk4 * 4];
#pragma unroll
            for (int i = 0; i < 4; ++i)
#pragma unroll
                for (int j = 0; j < 4; ++j) accv[i][j] += qf[i] * wf[j];
        }
        __syncthreads();
    }
#pragma unroll
    for (int i = 0; i < 4; ++i) {
        float4 w4;
        f4 p;
        p = accv[i][0]; w4.x = (p.x + p.y) + (p.z + p.w);
        p = accv[i][1]; w4.y = (p.x + p.y) + (p.z + p.w);
        p = accv[i][2]; w4.z = (p.x + p.y) + (p.z + p.w);
        p = accv[i][3]; w4.w = (p.x + p.y) + (p.z + p.w);
        *(float4*)&gpart[(blockIdx.y * 64 + ty * 4 + i) * NO + o0 + tx * 4] = w4;
    }
}

// ---------------- K1b: reduce k-splits + bias, transpose to kern[w][b][c]; zero cnt
__global__ __launch_bounds__(256) void k1b_reduce(const float* __restrict__ gpart,
                                                  const float* __restrict__ bias,
                                                  float* __restrict__ kern,
                                                  int* __restrict__ cnt) {
    if (blockIdx.x == 0 && threadIdx.x < Bn) cnt[threadIdx.x] = 0;
    int idx = blockIdx.x * 256 + threadIdx.x;
    if (idx >= 3 * Bn * Cn) return;
    int w = idx / (Bn * Cn);
    int rem = idx - w * (Bn * Cn);
    int b = rem >> 9;
    int c = rem & 511;
    int o = c * 3 + w;
    float s = bias[o];
#pragma unroll
    for (int ks = 0; ks < 4; ++ks) s += gpart[(ks * Bn + b) * NO + o];
    kern[idx] = s;
}

// ---------------- K2 (R2/R5 variant): dplP[w][b][8+t] = k[t,b,:]·kern[w][b][:]; wave=(b, 8 t's)
__global__ __launch_bounds__(256) void k2_dots(const float* __restrict__ kin,
                                               const float* __restrict__ kern,
                                               float* __restrict__ dplP) {
    const int wid = (blockIdx.x << 2) + (threadIdx.x >> 6);
    const int lane = threadIdx.x & 63;
    const int b = wid & 63;
    const int t0 = (wid >> 6) << 3;

    f4 kwA[3], kwB[3];
#pragma unroll
    for (int w = 0; w < 3; ++w) {
        const f4* p = (const f4*)(kern + (w * Bn + b) * Cn);
        kwA[w] = p[lane];
        kwB[w] = p[64 + lane];
    }
#pragma unroll
    for (int ti = 0; ti < 8; ++ti) {
        const int t = t0 + ti;
        const f4* kr = (const f4*)(kin + ((size_t)t * Bn + b) * Cn);
        f4 a = __builtin_nontemporal_load(kr + lane);
        f4 c = __builtin_nontemporal_load(kr + 64 + lane);
        float acc0 = a.x * kwA[0].x + a.y * kwA[0].y + a.z * kwA[0].z + a.w * kwA[0].w
                   + c.x * kwB[0].x + c.y * kwB[0].y + c.z * kwB[0].z + c.w * kwB[0].w;
        float acc1 = a.x * kwA[1].x + a.y * kwA[1].y + a.z * kwA[1].z + a.w * kwA[1].w
                   + c.x * kwB[1].x + c.y * kwB[1].y + c.z * kwB[1].z + c.w * kwB[1].w;
        float acc2 = a.x * kwA[2].x + a.y * kwA[2].y + a.z * kwA[2].z + a.w * kwA[2].w
                   + c.x * kwB[2].x + c.y * kwB[2].y + c.z * kwB[2].z + c.w * kwB[2].w;
#pragma unroll
        for (int off = 32; off; off >>= 1) {
            acc0 += __shfl_xor(acc0, off);
            acc1 += __shfl_xor(acc1, off);
            acc2 += __shfl_xor(acc2, off);
        }
        if (lane == 0) {
            dplP[(0 * Bn + b) * DROW + DPAD + t] = acc0;
            dplP[(1 * Bn + b) * DROW + DPAD + t] = acc1;
            dplP[(2 * Bn + b) * DROW + DPAD + t] = acc2;
        }
    }
}

// ---------------- KAB: taps+aBT+chunk-stats | per-b software barrier | e+eT+sparse PV
// grid 256 = (h 0..3) x (b 0..63); all blocks co-resident (<=1/CU, bounds ensure 2/CU cap).
__global__ __launch_bounds__(256, 2) void kAB(const float* __restrict__ dplP,
                                              const int* __restrict__ kmask,
                                              const float* __restrict__ v,
                                              float* __restrict__ aBT,
                                              float* __restrict__ eT,
                                              float* __restrict__ cstat,
                                              int* __restrict__ cnt,
                                              float* __restrict__ vpart) {
    const int b = blockIdx.x & 63;
    const int h = blockIdx.x >> 6;       // 0..3, 512-t half-chunks
    const int tid = threadIdx.x;
    const int t1 = h * 512 + tid;
    const int t2 = t1 + 256;

    __shared__ float red[4];
    __shared__ float sh[2];
    __shared__ float es[512];
    __shared__ unsigned long long bm[8];

    // ---- phase 1: combine taps, write aBT, chunk stats over 512 t ----
    const float* d0 = dplP + (0 * Bn + b) * DROW + DPAD;
    const float* d1 = dplP + (1 * Bn + b) * DROW + DPAD;
    const float* d2 = dplP + (2 * Bn + b) * DROW + DPAD;
    const float x01 = d0[t1 - 1], x21 = d2[t1 + 1];
    const float a1 = d1[t1] + (t1 > 0 ? x01 : 0.f) + (t1 < Ln - 1 ? x21 : 0.f);
    const float x02 = d0[t2 - 1], x22 = d2[t2 + 1];
    const float a2 = d1[t2] + (t2 > 0 ? x02 : 0.f) + (t2 < Ln - 1 ? x22 : 0.f);
    const int m1 = kmask[t1 * Bn + b];
    const int m2 = kmask[t2 * Bn + b];
    aBT[b * Ln + t1] = a1;
    aBT[b * Ln + t2] = a2;

    float lmax = fmaxf(m1 ? a1 : -FLT_MAX, m2 ? a2 : -FLT_MAX);
#pragma unroll
    for (int off = 32; off; off >>= 1) lmax = fmaxf(lmax, __shfl_xor(lmax, off));
    if ((tid & 63) == 0) red[tid >> 6] = lmax;
    __syncthreads();
    const float mxc = fmaxf(fmaxf(red[0], red[1]), fmaxf(red[2], red[3]));
    __syncthreads();
    float lsum = (m1 ? __expf(a1 - mxc) : 0.f) + (m2 ? __expf(a2 - mxc) : 0.f);
#pragma unroll
    for (int off = 32; off; off >>= 1) lsum += __shfl_xor(lsum, off);
    if ((tid & 63) == 0) red[tid >> 6] = lsum;
    __syncthreads();

    // ---- per-b software barrier among the 4 blocks of this b ----
    if (tid == 0) {
        cstat[b * 16 + h * 2 + 0] = mxc;
        cstat[b * 16 + h * 2 + 1] = red[0] + red[1] + red[2] + red[3];
        __threadfence();                       // release cstat
        atomicAdd(&cnt[b], 1);                 // device-scope
        while (atomicAdd(&cnt[b], 0) < 4) {}   // spin (atomic read)
        __threadfence();                       // acquire
        const float* cs = cstat + b * 16;
        float mx = -FLT_MAX;
#pragma unroll
        for (int j = 0; j < 4; ++j)
            if (cs[2 * j + 1] > 0.f) mx = fmaxf(mx, cs[2 * j]);
        float sum = 0.f;
#pragma unroll
        for (int j = 0; j < 4; ++j)
            if (cs[2 * j + 1] > 0.f) sum += cs[2 * j + 1] * __expf(cs[2 * j] - mx);
        sh[0] = mx;
        sh[1] = 1.f / sum;
    }
    __syncthreads();
    const float mx = sh[0];
    const float inv = sh[1];

    // ---- phase 2: e, eT, ballot-sparse PV over this block's 512 t ----
    const float e1 = m1 ? __expf(a1 - mx) * inv : 0.f;
    const float e2 = m2 ? __expf(a2 - mx) * inv : 0.f;
    eT[b * Ln + t1] = e1;
    eT[b * Ln + t2] = e2;
    es[tid] = e1;
    es[256 + tid] = e2;
    unsigned long long bal1 = __ballot(e1 != 0.f);
    unsigned long long bal2 = __ballot(e2 != 0.f);
    if ((tid & 63) == 0) {
        bm[tid >> 6] = bal1;
        bm[4 + (tid >> 6)] = bal2;
    }
    __syncthreads();

    f2 a0 = (f2)0.f, a1v = (f2)0.f;
#pragma unroll
    for (int w = 0; w < 8; ++w) {
        unsigned long long mm = bm[w];
        while (mm) {
            int bit = __ffsll(mm) - 1;
            mm &= mm - 1;
            int tt = w * 64 + bit;                 // 0..511 within this half
            float ee = es[tt];
            const f2* vrow = (const f2*)(v + (((size_t)(h * 512 + tt) * Bn + b) << 9));
            f2 vv = __builtin_nontemporal_load(vrow + tid);
            if (mm) {      // keep 2 loads in flight
                int bit2 = __ffsll(mm) - 1;
                mm &= mm - 1;
                int tt2 = w * 64 + bit2;
                float ee2 = es[tt2];
                const f2* vrow2 = (const f2*)(v + (((size_t)(h * 512 + tt2) * Bn + b) << 9));
                f2 vv2 = __builtin_nontemporal_load(vrow2 + tid);
                a0 += ee * vv;
                a1v += ee2 * vv2;
            } else {
                a0 += ee * vv;
            }
        }
    }
    f2 s = a0 + a1v;
    *(f2*)&vpart[((h * Bn + b) << 9) + tid * 2] = s;
}

// ---------------- KC: blocks 0..127 transpose-emit out_a/out_e; 128..255 reduce vpart
__global__ __launch_bounds__(256) void kC_fin(const float* __restrict__ aBT,
                                              const float* __restrict__ eT,
                                              const float* __restrict__ vpart,
                                              float* __restrict__ out_a,
                                              float* __restrict__ out_e,
                                              float* __restrict__ out_att) {
    const int bid = blockIdx.x;
    const int tid = threadIdx.x;
    __shared__ __align__(16) float lsa[64][17];
    __shared__ __align__(16) float lse[64][17];

    if (bid < 128) {
        const int t0 = bid * 16;
        const int rb = tid >> 2;       // 0..63  (b)
        const int ri = tid & 3;        // 0..3   (f4 group within 16 t)
        f4 av = *(const f4*)&aBT[rb * Ln + t0 + ri * 4];
        f4 ev = *(const f4*)&eT[rb * Ln + t0 + ri * 4];
#pragma unroll
        for (int j = 0; j < 4; ++j) {
            lsa[rb][ri * 4 + j] = av[j];
            lse[rb][ri * 4 + j] = ev[j];
        }
        __syncthreads();
        const int tt = tid >> 4;       // 0..15
        const int c4 = tid & 15;       // 0..15
        f4 oa, oe;
#pragma unroll
        for (int j = 0; j < 4; ++j) {
            oa[j] = lsa[c4 * 4 + j][tt];
            oe[j] = lse[c4 * 4 + j][tt];
        }
        *(f4*)&out_a[(t0 + tt) * Bn + c4 * 4] = oa;
        *(f4*)&out_e[(t0 + tt) * Bn + c4 * 4] = oe;
    } else {
        const int idx = (bid - 128) * 256 + tid;   // [0, 32768)
        float s = 0.f;
#pragma unroll
        for (int cc = 0; cc < 4; ++cc) s += vpart[cc * (Bn * Vn) + idx];
        out_att[idx] = s;
    }
}

extern "C" void kernel_launch(void* const* d_in, const int* in_sizes, int n_in,
                              void* d_out, int out_size, void* d_ws, size_t ws_size,
                              hipStream_t stream) {
    const float* q = (const float*)d_in[0];
    const float* k = (const float*)d_in[1];
    const float* v = (const float*)d_in[2];
    const int* kmask = (const int*)d_in[3];
    const float* W = (const float*)d_in[4];
    const float* bias = (const float*)d_in[5];

    float* out = (float*)d_out;
    float* out_a = out;                      // [L, B]
    float* out_e = out + Ln * Bn;            // [L, B]
    float* out_att = out + 2 * Ln * Bn;      // [B, V]

    float* ws = (float*)d_ws;
    float* kern = ws + OFF_KERN;
    float* dplP = ws + OFF_DPL;
    float* aBT = ws + OFF_ABT;
    float* eT = ws + OFF_ET;
    float* cstat = ws + OFF_CST;
    int* cnt = (int*)(ws + OFF_CNT);
    float* scr = ws + OFF_SCR;   // gpart (k1 phase) then vpart (tail phase) — disjoint in time

    k1_gemm<<<dim3(24, 4), 256, 0, stream>>>(q, W, scr);
    k1b_reduce<<<(3 * Bn * Cn + 255) / 256, 256, 0, stream>>>(scr, bias, kern, cnt);
    k2_dots<<<4096, 256, 0, stream>>>(k, kern, dplP);
    kAB<<<256, 256, 0, stream>>>(dplP, kmask, v, aBT, eT, cstat, cnt, scr);
    kC_fin<<<256, 256, 0, stream>>>(aBT, eT, scr, out_a, out_e, out_att);
}

// Round 12
// 92.978 us; speedup vs baseline: 1.0978x; 1.0978x over previous
//
#include <hip/hip_runtime.h>
#include <float.h>
#include <math.h>

#define Ln 2048
#define Bn 64
#define Cn 512
#define Qn 512
#define Vn 512
#define NO 1536   // C*KW

#define DROW 2064   // padded dpl row: 8 front pad + 2048 + 8 tail pad
#define DPAD 8

// workspace layout (in floats)
#define OFF_KERN 0                                   // kern[3][B][C]   = 98304
#define OFF_DPL  98304                               // dplP[3][B][DROW]= 396288
#define OFF_ABT  (OFF_DPL + 396288)                  // aBT[b][t]       = 131072
#define OFF_ET   (OFF_ABT + 131072)                  // eT[b][t]        = 131072
#define OFF_CST  (OFF_ET + 131072)                   // cstat[B][8][2]  = 1024
#define OFF_SCR  (OFF_CST + 1024)                    // gpart(393216) / vpart(262144)

typedef float f4 __attribute__((ext_vector_type(4)));
typedef float f2 __attribute__((ext_vector_type(2)));

// ---------------- K1: gpart[ks][b][o] = sum_{k in split} q[b,k] W[o,k]
__global__ __launch_bounds__(256) void k1_gemm(const float* __restrict__ q,
                                               const float* __restrict__ W,
                                               float* __restrict__ gpart) {
    __shared__ __align__(16) float qs[64][68];
    __shared__ __align__(16) float wsm[64][68];
    const int o0 = blockIdx.x * 64;
    const int k0 = blockIdx.y * 128;
    const int tid = threadIdx.x;
    const int ty = tid >> 4, tx = tid & 15;

    f4 accv[4][4];
#pragma unroll
    for (int i = 0; i < 4; ++i)
#pragma unroll
        for (int j = 0; j < 4; ++j) accv[i][j] = (f4)0.f;

    for (int kc = 0; kc < 128; kc += 64) {
#pragma unroll
        for (int r = 0; r < 4; ++r) {
            int idx = tid + r * 256;
            int row = idx >> 4;
            int c4 = (idx & 15) << 2;
            float4 vq = *(const float4*)&q[row * Qn + k0 + kc + c4];
            qs[row][c4 + 0] = vq.x; qs[row][c4 + 1] = vq.y;
            qs[row][c4 + 2] = vq.z; qs[row][c4 + 3] = vq.w;
            float4 vw = *(const float4*)&W[(o0 + row) * Qn + k0 + kc + c4];
            wsm[row][c4 + 0] = vw.x; wsm[row][c4 + 1] = vw.y;
            wsm[row][c4 + 2] = vw.z; wsm[row][c4 + 3] = vw.w;
        }
        __syncthreads();
#pragma unroll
        for (int kk4 = 0; kk4 < 16; ++kk4) {
            f4 qf[4], wf[4];
#pragma unroll
            for (int i = 0; i < 4; ++i) qf[i] = *(const f4*)&qs[ty * 4 + i][kk4 * 4];
#pragma unroll
            for (int j = 0; j < 4; ++j) wf[j] = *(const f4*)&wsm[tx * 4 + j][kk4 * 4];
#pragma unroll
            for (int i = 0; i < 4; ++i)
#pragma unroll
                for (int j = 0; j < 4; ++j) accv[i][j] += qf[i] * wf[j];
        }
        __syncthreads();
    }
#pragma unroll
    for (int i = 0; i < 4; ++i) {
        float4 w4;
        f4 p;
        p = accv[i][0]; w4.x = (p.x + p.y) + (p.z + p.w);
        p = accv[i][1]; w4.y = (p.x + p.y) + (p.z + p.w);
        p = accv[i][2]; w4.z = (p.x + p.y) + (p.z + p.w);
        p = accv[i][3]; w4.w = (p.x + p.y) + (p.z + p.w);
        *(float4*)&gpart[(blockIdx.y * 64 + ty * 4 + i) * NO + o0 + tx * 4] = w4;
    }
}

// ---------------- K1b: reduce k-splits + bias, transpose to kern[w][b][c]
__global__ __launch_bounds__(256) void k1b_reduce(const float* __restrict__ gpart,
                                                  const float* __restrict__ bias,
                                                  float* __restrict__ kern) {
    int idx = blockIdx.x * 256 + threadIdx.x;
    if (idx >= 3 * Bn * Cn) return;
    int w = idx / (Bn * Cn);
    int rem = idx - w * (Bn * Cn);
    int b = rem >> 9;
    int c = rem & 511;
    int o = c * 3 + w;
    float s = bias[o];
#pragma unroll
    for (int ks = 0; ks < 4; ++ks) s += gpart[(ks * Bn + b) * NO + o];
    kern[idx] = s;
}

// ---------------- K2 (R2/R5 variant): dplP[w][b][8+t] = k[t,b,:]·kern[w][b][:]; wave=(b, 8 t's)
__global__ __launch_bounds__(256) void k2_dots(const float* __restrict__ kin,
                                               const float* __restrict__ kern,
                                               float* __restrict__ dplP) {
    const int wid = (blockIdx.x << 2) + (threadIdx.x >> 6);
    const int lane = threadIdx.x & 63;
    const int b = wid & 63;
    const int t0 = (wid >> 6) << 3;

    f4 kwA[3], kwB[3];
#pragma unroll
    for (int w = 0; w < 3; ++w) {
        const f4* p = (const f4*)(kern + (w * Bn + b) * Cn);
        kwA[w] = p[lane];
        kwB[w] = p[64 + lane];
    }
#pragma unroll
    for (int ti = 0; ti < 8; ++ti) {
        const int t = t0 + ti;
        const f4* kr = (const f4*)(kin + ((size_t)t * Bn + b) * Cn);
        f4 a = __builtin_nontemporal_load(kr + lane);
        f4 c = __builtin_nontemporal_load(kr + 64 + lane);
        float acc0 = a.x * kwA[0].x + a.y * kwA[0].y + a.z * kwA[0].z + a.w * kwA[0].w
                   + c.x * kwB[0].x + c.y * kwB[0].y + c.z * kwB[0].z + c.w * kwB[0].w;
        float acc1 = a.x * kwA[1].x + a.y * kwA[1].y + a.z * kwA[1].z + a.w * kwA[1].w
                   + c.x * kwB[1].x + c.y * kwB[1].y + c.z * kwB[1].z + c.w * kwB[1].w;
        float acc2 = a.x * kwA[2].x + a.y * kwA[2].y + a.z * kwA[2].z + a.w * kwA[2].w
                   + c.x * kwB[2].x + c.y * kwB[2].y + c.z * kwB[2].z + c.w * kwB[2].w;
#pragma unroll
        for (int off = 32; off; off >>= 1) {
            acc0 += __shfl_xor(acc0, off);
            acc1 += __shfl_xor(acc1, off);
            acc2 += __shfl_xor(acc2, off);
        }
        if (lane == 0) {
            dplP[(0 * Bn + b) * DROW + DPAD + t] = acc0;
            dplP[(1 * Bn + b) * DROW + DPAD + t] = acc1;
            dplP[(2 * Bn + b) * DROW + DPAD + t] = acc2;
        }
    }
}

// ---------------- KA: combine taps -> aBT (coalesced) + per-chunk masked stats
__global__ __launch_bounds__(256) void kA_stats(const float* __restrict__ dplP,
                                                const int* __restrict__ kmask,
                                                float* __restrict__ aBT,
                                                float* __restrict__ cstat) {
    const int b = blockIdx.x & 63;
    const int c = blockIdx.x >> 6;
    const int tid = threadIdx.x;
    const int t = c * 256 + tid;
    __shared__ float red[4];

    const float* d0 = dplP + (0 * Bn + b) * DROW + DPAD;
    const float* d1 = dplP + (1 * Bn + b) * DROW + DPAD;
    const float* d2 = dplP + (2 * Bn + b) * DROW + DPAD;
    const float x0 = d0[t - 1];
    const float x2 = d2[t + 1];
    const float a = d1[t] + (t > 0 ? x0 : 0.f) + (t < Ln - 1 ? x2 : 0.f);
    const int m = kmask[t * Bn + b];
    aBT[b * Ln + t] = a;

    float lmax = m ? a : -FLT_MAX;
#pragma unroll
    for (int off = 32; off; off >>= 1) lmax = fmaxf(lmax, __shfl_xor(lmax, off));
    if ((tid & 63) == 0) red[tid >> 6] = lmax;
    __syncthreads();
    const float mxc = fmaxf(fmaxf(red[0], red[1]), fmaxf(red[2], red[3]));
    __syncthreads();
    float lsum = m ? __expf(a - mxc) : 0.f;
#pragma unroll
    for (int off = 32; off; off >>= 1) lsum += __shfl_xor(lsum, off);
    if ((tid & 63) == 0) red[tid >> 6] = lsum;
    __syncthreads();
    if (tid == 0) {
        cstat[(b * 8 + c) * 2 + 0] = mxc;
        cstat[(b * 8 + c) * 2 + 1] = red[0] + red[1] + red[2] + red[3];
    }
}

// ---------------- KB: combine stats in-reg, emit eT, ballot-sparse PV partials
__global__ __launch_bounds__(256) void kB_pv(const float* __restrict__ aBT,
                                             const int* __restrict__ kmask,
                                             const float* __restrict__ cstat,
                                             const float* __restrict__ v,
                                             float* __restrict__ eT,
                                             float* __restrict__ vpart) {
    const int b = blockIdx.x & 63;
    const int c = blockIdx.x >> 6;
    const int tid = threadIdx.x;
    const int t = c * 256 + tid;

    const float* cs = cstat + b * 16;
    float mx = -FLT_MAX;
#pragma unroll
    for (int j = 0; j < 8; ++j)
        if (cs[2 * j + 1] > 0.f) mx = fmaxf(mx, cs[2 * j]);
    float sum = 0.f;
#pragma unroll
    for (int j = 0; j < 8; ++j)
        if (cs[2 * j + 1] > 0.f) sum += cs[2 * j + 1] * __expf(cs[2 * j] - mx);
    const float inv = 1.f / sum;

    const float a = aBT[b * Ln + t];
    const int m = kmask[t * Bn + b];
    const float e = m ? __expf(a - mx) * inv : 0.f;
    eT[b * Ln + t] = e;

    __shared__ float es[256];
    __shared__ unsigned long long bm[4];
    es[tid] = e;
    unsigned long long bal = __ballot(e != 0.f);
    if ((tid & 63) == 0) bm[tid >> 6] = bal;
    __syncthreads();

    f2 a0 = (f2)0.f, a1 = (f2)0.f;
#pragma unroll
    for (int w = 0; w < 4; ++w) {
        unsigned long long mm = bm[w];
        while (mm) {
            int bit = __ffsll(mm) - 1;
            mm &= mm - 1;
            int tt = w * 64 + bit;
            float ee = es[tt];
            const f2* vrow = (const f2*)(v + (((size_t)(c * 256 + tt) * Bn + b) << 9));
            f2 vv = __builtin_nontemporal_load(vrow + tid);
            if (mm) {
                int bit2 = __ffsll(mm) - 1;
                mm &= mm - 1;
                int tt2 = w * 64 + bit2;
                float ee2 = es[tt2];
                const f2* vrow2 = (const f2*)(v + (((size_t)(c * 256 + tt2) * Bn + b) << 9));
                f2 vv2 = __builtin_nontemporal_load(vrow2 + tid);
                a0 += ee * vv;
                a1 += ee2 * vv2;
            } else {
                a0 += ee * vv;
            }
        }
    }
    f2 s = a0 + a1;
    *(f2*)&vpart[((c * Bn + b) << 9) + tid * 2] = s;
}

// ---------------- KC: blocks 0..127 transpose-emit out_a/out_e; 128..255 reduce vpart
__global__ __launch_bounds__(256) void kC_fin(const float* __restrict__ aBT,
                                              const float* __restrict__ eT,
                                              const float* __restrict__ vpart,
                                              float* __restrict__ out_a,
                                              float* __restrict__ out_e,
                                              float* __restrict__ out_att) {
    const int bid = blockIdx.x;
    const int tid = threadIdx.x;
    __shared__ __align__(16) float lsa[64][17];
    __shared__ __align__(16) float lse[64][17];

    if (bid < 128) {
        const int t0 = bid * 16;
        const int rb = tid >> 2;
        const int ri = tid & 3;
        f4 av = *(const f4*)&aBT[rb * Ln + t0 + ri * 4];
        f4 ev = *(const f4*)&eT[rb * Ln + t0 + ri * 4];
#pragma unroll
        for (int j = 0; j < 4; ++j) {
            lsa[rb][ri * 4 + j] = av[j];
            lse[rb][ri * 4 + j] = ev[j];
        }
        __syncthreads();
        const int tt = tid >> 4;
        const int c4 = tid & 15;
        f4 oa, oe;
#pragma unroll
        for (int j = 0; j < 4; ++j) {
            oa[j] = lsa[c4 * 4 + j][tt];
            oe[j] = lse[c4 * 4 + j][tt];
        }
        *(f4*)&out_a[(t0 + tt) * Bn + c4 * 4] = oa;
        *(f4*)&out_e[(t0 + tt) * Bn + c4 * 4] = oe;
    } else {
        const int idx = (bid - 128) * 256 + tid;
        float s = 0.f;
#pragma unroll
        for (int cc = 0; cc < 8; ++cc) s += vpart[cc * (Bn * Vn) + idx];
        out_att[idx] = s;
    }
}

// ---------------- MEASUREMENT: empty kernel, same dispatch shape as tail kernels
__global__ __launch_bounds__(256) void kEmpty() {}

extern "C" void kernel_launch(void* const* d_in, const int* in_sizes, int n_in,
                              void* d_out, int out_size, void* d_ws, size_t ws_size,
                              hipStream_t stream) {
    const float* q = (const float*)d_in[0];
    const float* k = (const float*)d_in[1];
    const float* v = (const float*)d_in[2];
    const int* kmask = (const int*)d_in[3];
    const float* W = (const float*)d_in[4];
    const float* bias = (const float*)d_in[5];

    float* out = (float*)d_out;
    float* out_a = out;                      // [L, B]
    float* out_e = out + Ln * Bn;            // [L, B]
    float* out_att = out + 2 * Ln * Bn;      // [B, V]

    float* ws = (float*)d_ws;
    float* kern = ws + OFF_KERN;
    float* dplP = ws + OFF_DPL;
    float* aBT = ws + OFF_ABT;
    float* eT = ws + OFF_ET;
    float* cstat = ws + OFF_CST;
    float* scr = ws + OFF_SCR;

    k1_gemm<<<dim3(24, 4), 256, 0, stream>>>(q, W, scr);
    k1b_reduce<<<(3 * Bn * Cn + 255) / 256, 256, 0, stream>>>(scr, bias, kern);
    k2_dots<<<4096, 256, 0, stream>>>(k, kern, dplP);
    kA_stats<<<512, 256, 0, stream>>>(dplP, kmask, aBT, cstat);
    // MEASUREMENT: 6 empty graph nodes chained in — delta vs R9 (84.3) = 6 x node overhead
    kEmpty<<<256, 256, 0, stream>>>();
    kEmpty<<<256, 256, 0, stream>>>();
    kEmpty<<<256, 256, 0, stream>>>();
    kB_pv<<<512, 256, 0, stream>>>(aBT, kmask, cstat, v, eT, scr);
    kEmpty<<<256, 256, 0, stream>>>();
    kEmpty<<<256, 256, 0, stream>>>();
    kEmpty<<<256, 256, 0, stream>>>();
    kC_fin<<<256, 256, 0, stream>>>(aBT, eT, scr, out_a, out_e, out_att);
}

// Round 13
// 78.911 us; speedup vs baseline: 1.2935x; 1.1783x over previous
//
#include <hip/hip_runtime.h>
#include <float.h>
#include <math.h>

#define Ln 2048
#define Bn 64
#define Cn 512
#define Qn 512
#define Vn 512
#define NO 1536   // C*KW

#define DROW 2064   // padded dpl row: 8 front pad + 2048 + 8 tail pad
#define DPAD 8

// workspace layout (in floats)
#define OFF_KERN 0                                   // kern[3][B][C]   = 98304
#define OFF_DPL  98304                               // dplP[3][B][DROW]= 396288
#define OFF_ABT  (OFF_DPL + 396288)                  // aBTm[b][t]      = 131072 (masked: a or -1e30)
#define OFF_CST  (OFF_ABT + 131072)                  // cstat[B][8][2]  = 1024
#define OFF_SCR  (OFF_CST + 1024)                    // gpart(393216) / vpart(262144)

typedef float f4 __attribute__((ext_vector_type(4)));
typedef float f2 __attribute__((ext_vector_type(2)));

// ---------------- K1: gpart[ks][b][o] = sum_{k in split} q[b,k] W[o,k]
__global__ __launch_bounds__(256) void k1_gemm(const float* __restrict__ q,
                                               const float* __restrict__ W,
                                               float* __restrict__ gpart) {
    __shared__ __align__(16) float qs[64][68];
    __shared__ __align__(16) float wsm[64][68];
    const int o0 = blockIdx.x * 64;
    const int k0 = blockIdx.y * 128;
    const int tid = threadIdx.x;
    const int ty = tid >> 4, tx = tid & 15;

    f4 accv[4][4];
#pragma unroll
    for (int i = 0; i < 4; ++i)
#pragma unroll
        for (int j = 0; j < 4; ++j) accv[i][j] = (f4)0.f;

    for (int kc = 0; kc < 128; kc += 64) {
#pragma unroll
        for (int r = 0; r < 4; ++r) {
            int idx = tid + r * 256;
            int row = idx >> 4;
            int c4 = (idx & 15) << 2;
            float4 vq = *(const float4*)&q[row * Qn + k0 + kc + c4];
            qs[row][c4 + 0] = vq.x; qs[row][c4 + 1] = vq.y;
            qs[row][c4 + 2] = vq.z; qs[row][c4 + 3] = vq.w;
            float4 vw = *(const float4*)&W[(o0 + row) * Qn + k0 + kc + c4];
            wsm[row][c4 + 0] = vw.x; wsm[row][c4 + 1] = vw.y;
            wsm[row][c4 + 2] = vw.z; wsm[row][c4 + 3] = vw.w;
        }
        __syncthreads();
#pragma unroll
        for (int kk4 = 0; kk4 < 16; ++kk4) {
            f4 qf[4], wf[4];
#pragma unroll
            for (int i = 0; i < 4; ++i) qf[i] = *(const f4*)&qs[ty * 4 + i][kk4 * 4];
#pragma unroll
            for (int j = 0; j < 4; ++j) wf[j] = *(const f4*)&wsm[tx * 4 + j][kk4 * 4];
#pragma unroll
            for (int i = 0; i < 4; ++i)
#pragma unroll
                for (int j = 0; j < 4; ++j) accv[i][j] += qf[i] * wf[j];
        }
        __syncthreads();
    }
#pragma unroll
    for (int i = 0; i < 4; ++i) {
        float4 w4;
        f4 p;
        p = accv[i][0]; w4.x = (p.x + p.y) + (p.z + p.w);
        p = accv[i][1]; w4.y = (p.x + p.y) + (p.z + p.w);
        p = accv[i][2]; w4.z = (p.x + p.y) + (p.z + p.w);
        p = accv[i][3]; w4.w = (p.x + p.y) + (p.z + p.w);
        *(float4*)&gpart[(blockIdx.y * 64 + ty * 4 + i) * NO + o0 + tx * 4] = w4;
    }
}

// ---------------- K1b: reduce k-splits + bias, transpose to kern[w][b][c]
__global__ __launch_bounds__(256) void k1b_reduce(const float* __restrict__ gpart,
                                                  const float* __restrict__ bias,
                                                  float* __restrict__ kern) {
    int idx = blockIdx.x * 256 + threadIdx.x;
    if (idx >= 3 * Bn * Cn) return;
    int w = idx / (Bn * Cn);
    int rem = idx - w * (Bn * Cn);
    int b = rem >> 9;
    int c = rem & 511;
    int o = c * 3 + w;
    float s = bias[o];
#pragma unroll
    for (int ks = 0; ks < 4; ++ks) s += gpart[(ks * Bn + b) * NO + o];
    kern[idx] = s;
}

// ---------------- K2 (R2/R5 variant): dplP[w][b][8+t] = k[t,b,:]·kern[w][b][:]; wave=(b, 8 t's)
__global__ __launch_bounds__(256) void k2_dots(const float* __restrict__ kin,
                                               const float* __restrict__ kern,
                                               float* __restrict__ dplP) {
    const int wid = (blockIdx.x << 2) + (threadIdx.x >> 6);
    const int lane = threadIdx.x & 63;
    const int b = wid & 63;
    const int t0 = (wid >> 6) << 3;

    f4 kwA[3], kwB[3];
#pragma unroll
    for (int w = 0; w < 3; ++w) {
        const f4* p = (const f4*)(kern + (w * Bn + b) * Cn);
        kwA[w] = p[lane];
        kwB[w] = p[64 + lane];
    }
#pragma unroll
    for (int ti = 0; ti < 8; ++ti) {
        const int t = t0 + ti;
        const f4* kr = (const f4*)(kin + ((size_t)t * Bn + b) * Cn);
        f4 a = __builtin_nontemporal_load(kr + lane);
        f4 c = __builtin_nontemporal_load(kr + 64 + lane);
        float acc0 = a.x * kwA[0].x + a.y * kwA[0].y + a.z * kwA[0].z + a.w * kwA[0].w
                   + c.x * kwB[0].x + c.y * kwB[0].y + c.z * kwB[0].z + c.w * kwB[0].w;
        float acc1 = a.x * kwA[1].x + a.y * kwA[1].y + a.z * kwA[1].z + a.w * kwA[1].w
                   + c.x * kwB[1].x + c.y * kwB[1].y + c.z * kwB[1].z + c.w * kwB[1].w;
        float acc2 = a.x * kwA[2].x + a.y * kwA[2].y + a.z * kwA[2].z + a.w * kwA[2].w
                   + c.x * kwB[2].x + c.y * kwB[2].y + c.z * kwB[2].z + c.w * kwB[2].w;
#pragma unroll
        for (int off = 32; off; off >>= 1) {
            acc0 += __shfl_xor(acc0, off);
            acc1 += __shfl_xor(acc1, off);
            acc2 += __shfl_xor(acc2, off);
        }
        if (lane == 0) {
            dplP[(0 * Bn + b) * DROW + DPAD + t] = acc0;
            dplP[(1 * Bn + b) * DROW + DPAD + t] = acc1;
            dplP[(2 * Bn + b) * DROW + DPAD + t] = acc2;
        }
    }
}

// ---------------- KA: taps -> out_a (direct scattered) + aBTm (masked, coalesced) + chunk stats
// grid 512 = (c 0..7) x (b 0..63)
__global__ __launch_bounds__(256) void kA_stats(const float* __restrict__ dplP,
                                                const int* __restrict__ kmask,
                                                float* __restrict__ out_a,
                                                float* __restrict__ aBTm,
                                                float* __restrict__ cstat) {
    const int b = blockIdx.x & 63;
    const int c = blockIdx.x >> 6;
    const int tid = threadIdx.x;
    const int t = c * 256 + tid;
    __shared__ float red[4];

    const float* d0 = dplP + (0 * Bn + b) * DROW + DPAD;
    const float* d1 = dplP + (1 * Bn + b) * DROW + DPAD;
    const float* d2 = dplP + (2 * Bn + b) * DROW + DPAD;
    const float x0 = d0[t - 1];
    const float x2 = d2[t + 1];
    const float a = d1[t] + (t > 0 ? x0 : 0.f) + (t < Ln - 1 ? x2 : 0.f);
    const int m = kmask[t * Bn + b];
    out_a[t * Bn + b] = a;                       // direct scattered emit (full occupancy)
    aBTm[b * Ln + t] = m ? a : -1e30f;           // masked value for kB (no kmask read there)

    float lmax = m ? a : -FLT_MAX;
#pragma unroll
    for (int off = 32; off; off >>= 1) lmax = fmaxf(lmax, __shfl_xor(lmax, off));
    if ((tid & 63) == 0) red[tid >> 6] = lmax;
    __syncthreads();
    const float mxc = fmaxf(fmaxf(red[0], red[1]), fmaxf(red[2], red[3]));
    __syncthreads();
    float lsum = m ? __expf(a - mxc) : 0.f;
#pragma unroll
    for (int off = 32; off; off >>= 1) lsum += __shfl_xor(lsum, off);
    if ((tid & 63) == 0) red[tid >> 6] = lsum;
    __syncthreads();
    if (tid == 0) {
        cstat[(b * 8 + c) * 2 + 0] = mxc;
        cstat[(b * 8 + c) * 2 + 1] = red[0] + red[1] + red[2] + red[3];
    }
}

// ---------------- KB: combine stats, e -> out_e (direct), 4-deep ballot-sparse PV
// grid 512 = (c 0..7) x (b 0..63)
__global__ __launch_bounds__(256) void kB_pv(const float* __restrict__ aBTm,
                                             const float* __restrict__ cstat,
                                             const float* __restrict__ v,
                                             float* __restrict__ out_e,
                                             float* __restrict__ vpart) {
    const int b = blockIdx.x & 63;
    const int c = blockIdx.x >> 6;
    const int tid = threadIdx.x;
    const int t = c * 256 + tid;

    // uniform in-register combine of the 8 chunk stats for this b
    const float* cs = cstat + b * 16;
    float mx = -FLT_MAX;
#pragma unroll
    for (int j = 0; j < 8; ++j)
        if (cs[2 * j + 1] > 0.f) mx = fmaxf(mx, cs[2 * j]);
    float sum = 0.f;
#pragma unroll
    for (int j = 0; j < 8; ++j)
        if (cs[2 * j + 1] > 0.f) sum += cs[2 * j + 1] * __expf(cs[2 * j] - mx);
    const float inv = 1.f / sum;

    const float am = aBTm[b * Ln + t];           // -1e30 where masked -> e == 0
    const float e = __expf(am - mx) * inv;
    out_e[t * Bn + b] = e;                       // direct scattered emit

    __shared__ float es[256];
    __shared__ unsigned long long bm[4];
    __shared__ int lst[256];
    es[tid] = e;
    const unsigned long long bal = __ballot(e != 0.f);
    if ((tid & 63) == 0) bm[tid >> 6] = bal;
    __syncthreads();

    // wave-parallel compaction of nonzero indices into lst (ascending, deterministic)
    const int wv = tid >> 6;
    const int lane = tid & 63;
    int off = 0;
#pragma unroll
    for (int w = 0; w < 4; ++w)
        if (w < wv) off += __popcll(bm[w]);
    if (e != 0.f) {
        int rank = __popcll(bal & ((1ull << lane) - 1ull));
        lst[off + rank] = tid;
    }
    const int n = __popcll(bm[0]) + __popcll(bm[1]) + __popcll(bm[2]) + __popcll(bm[3]);
    __syncthreads();

    // 4-deep pipelined sparse PV
    f2 a0 = (f2)0.f, a1 = (f2)0.f, a2 = (f2)0.f, a3 = (f2)0.f;
    int i = 0;
    for (; i + 4 <= n; i += 4) {
        const int t0 = lst[i], t1 = lst[i + 1], t2 = lst[i + 2], t3 = lst[i + 3];
        const f2 v0 = __builtin_nontemporal_load((const f2*)(v + (((size_t)(c * 256 + t0) * Bn + b) << 9)) + tid);
        const f2 v1 = __builtin_nontemporal_load((const f2*)(v + (((size_t)(c * 256 + t1) * Bn + b) << 9)) + tid);
        const f2 v2 = __builtin_nontemporal_load((const f2*)(v + (((size_t)(c * 256 + t2) * Bn + b) << 9)) + tid);
        const f2 v3 = __builtin_nontemporal_load((const f2*)(v + (((size_t)(c * 256 + t3) * Bn + b) << 9)) + tid);
        a0 += es[t0] * v0;
        a1 += es[t1] * v1;
        a2 += es[t2] * v2;
        a3 += es[t3] * v3;
    }
    for (; i < n; ++i) {
        const int tt = lst[i];
        const f2 vv = __builtin_nontemporal_load((const f2*)(v + (((size_t)(c * 256 + tt) * Bn + b) << 9)) + tid);
        a0 += es[tt] * vv;
    }
    const f2 s = (a0 + a1) + (a2 + a3);
    *(f2*)&vpart[((c * Bn + b) << 9) + tid * 2] = s;
}

// ---------------- KC: reduce vpart -> attend[b, v]  (128 blocks)
__global__ __launch_bounds__(256) void kC_fin(const float* __restrict__ vpart,
                                              float* __restrict__ out_att) {
    const int idx = blockIdx.x * 256 + threadIdx.x;   // [0, 32768)
    float s = 0.f;
#pragma unroll
    for (int cc = 0; cc < 8; ++cc) s += vpart[cc * (Bn * Vn) + idx];
    out_att[idx] = s;
}

extern "C" void kernel_launch(void* const* d_in, const int* in_sizes, int n_in,
                              void* d_out, int out_size, void* d_ws, size_t ws_size,
                              hipStream_t stream) {
    const float* q = (const float*)d_in[0];
    const float* k = (const float*)d_in[1];
    const float* v = (const float*)d_in[2];
    const int* kmask = (const int*)d_in[3];
    const float* W = (const float*)d_in[4];
    const float* bias = (const float*)d_in[5];

    float* out = (float*)d_out;
    float* out_a = out;                      // [L, B]
    float* out_e = out + Ln * Bn;            // [L, B]
    float* out_att = out + 2 * Ln * Bn;      // [B, V]

    float* ws = (float*)d_ws;
    float* kern = ws + OFF_KERN;
    float* dplP = ws + OFF_DPL;
    float* aBTm = ws + OFF_ABT;
    float* cstat = ws + OFF_CST;
    float* scr = ws + OFF_SCR;   // gpart (k1 phase) then vpart (tail phase) — disjoint in time

    k1_gemm<<<dim3(24, 4), 256, 0, stream>>>(q, W, scr);
    k1b_reduce<<<(3 * Bn * Cn + 255) / 256, 256, 0, stream>>>(scr, bias, kern);
    k2_dots<<<4096, 256, 0, stream>>>(k, kern, dplP);
    kA_stats<<<512, 256, 0, stream>>>(dplP, kmask, out_a, aBTm, cstat);
    kB_pv<<<512, 256, 0, stream>>>(aBTm, cstat, v, out_e, scr);
    kC_fin<<<128, 256, 0, stream>>>(scr, out_att);
}